// Round 1
// baseline (378.681 us; speedup 1.0000x reference)
//
#include <hip/hip_runtime.h>
#include <stdint.h>

#define NTOK 8192
#define DIM 1024
#define EDIM 2048

typedef __attribute__((ext_vector_type(8))) short bf16x8;
typedef __attribute__((ext_vector_type(4))) float f32x4;

__device__ __forceinline__ unsigned short f2bf(float f) {
  union { float f; unsigned u; } v; v.f = f;
  unsigned r = (v.u + 0x7FFF + ((v.u >> 16) & 1)) >> 16;
  return (unsigned short)r;
}

__device__ __forceinline__ void gload16(const void* g, void* l) {
  __builtin_amdgcn_global_load_lds(
      (const __attribute__((address_space(1))) unsigned int*)g,
      (__attribute__((address_space(3))) unsigned int*)l, 16, 0, 0);
}

// ---------------- x -> bf16 (also zeroes the expert counters) ----------------
__global__ void cvt_x_k(const float* __restrict__ x, unsigned short* __restrict__ xb,
                        int* __restrict__ counts) {
  if (blockIdx.x == 0 && threadIdx.x == 0) { counts[0] = 0; counts[1] = 0; }
  int i = blockIdx.x * 256 + threadIdx.x;           // one thread = 8 elements
  const float4* p = (const float4*)x;
  float4 a = p[i * 2], b = p[i * 2 + 1];
  union { unsigned short s[8]; uint4 v; } o;
  o.s[0] = f2bf(a.x); o.s[1] = f2bf(a.y); o.s[2] = f2bf(a.z); o.s[3] = f2bf(a.w);
  o.s[4] = f2bf(b.x); o.s[5] = f2bf(b.y); o.s[6] = f2bf(b.z); o.s[7] = f2bf(b.w);
  ((uint4*)xb)[i] = o.v;
}

// ---------------- transpose + cast all weight matrices to [N][K] bf16 --------
__global__ void trans_k(const float* __restrict__ Sg, const float* __restrict__ Su,
                        const float* __restrict__ Sd, const float* __restrict__ Wg,
                        const float* __restrict__ Wu, const float* __restrict__ Wd,
                        unsigned short* __restrict__ wt) {
  const int id = blockIdx.y;
  const size_t MSZ = (size_t)DIM * EDIM;
  const float* src; int R, C;
  switch (id) {
    case 0: src = Sg;       R = DIM;  C = EDIM; break;
    case 1: src = Su;       R = DIM;  C = EDIM; break;
    case 2: src = Sd;       R = EDIM; C = DIM;  break;
    case 3: src = Wg;       R = DIM;  C = EDIM; break;
    case 4: src = Wg + MSZ; R = DIM;  C = EDIM; break;
    case 5: src = Wu;       R = DIM;  C = EDIM; break;
    case 6: src = Wu + MSZ; R = DIM;  C = EDIM; break;
    case 7: src = Wd;       R = EDIM; C = DIM;  break;
    default: src = Wd + MSZ; R = EDIM; C = DIM;  break;
  }
  unsigned short* dst = wt + (size_t)id * MSZ;
  __shared__ float tile[32][33];
  int tC = C >> 5;
  int tr = blockIdx.x / tC, tc = blockIdx.x % tC;
  int xt = threadIdx.x, yt = threadIdx.y;
  #pragma unroll
  for (int j = 0; j < 4; ++j)
    tile[yt + j * 8][xt] = src[(size_t)(tr * 32 + yt + j * 8) * C + tc * 32 + xt];
  __syncthreads();
  #pragma unroll
  for (int j = 0; j < 4; ++j)
    dst[(size_t)(tc * 32 + yt + j * 8) * R + tr * 32 + xt] = f2bf(tile[xt][yt + j * 8]);
}

// ---------------- router: argmax(logits + bias), compacted row lists ---------
__global__ void router_k(const float* __restrict__ x, const float* __restrict__ Wr,
                         const float* __restrict__ bias, int* __restrict__ counts,
                         int* __restrict__ rowlist) {
  int wid = threadIdx.x >> 6, lane = threadIdx.x & 63;
  int n = blockIdx.x * 4 + wid;
  const float* xr = x + (size_t)n * DIM;
  const float2* wr = (const float2*)Wr;
  float s0 = 0.f, s1 = 0.f;
  for (int d = lane; d < DIM; d += 64) {
    float xv = xr[d];
    float2 w = wr[d];
    s0 += xv * w.x; s1 += xv * w.y;
  }
  #pragma unroll
  for (int off = 32; off; off >>= 1) {
    s0 += __shfl_xor(s0, off);
    s1 += __shfl_xor(s1, off);
  }
  if (lane == 0) {
    int e = (s1 + bias[1] > s0 + bias[0]) ? 1 : 0;
    int pos = atomicAdd(&counts[e], 1);
    rowlist[e * NTOK + pos] = n;
  }
}

// ---------------- fused gate+up GEMM -> h = silu(x@Wg)*(x@Wu), bf16 ----------
template<bool GATHER>
__global__ __launch_bounds__(256, 2)
void up_k(const unsigned short* __restrict__ xb, const unsigned short* __restrict__ Bg0,
          const unsigned short* __restrict__ Bu0, const int* __restrict__ counts,
          const int* __restrict__ rowlist, unsigned short* __restrict__ h) {
  int mt, cnt;
  const int* rl = nullptr;
  const unsigned short* Bg = Bg0;
  const unsigned short* Bu = Bu0;
  if (GATHER) {
    int e = blockIdx.x >> 6;
    mt = blockIdx.x & 63;
    cnt = counts[e];
    if (mt * 128 >= cnt) return;
    rl = rowlist + e * NTOK;
    size_t off = (size_t)e * ((size_t)DIM * EDIM);
    Bg = Bg0 + off; Bu = Bu0 + off;
  } else { mt = blockIdx.x; cnt = NTOK; }

  const int t = threadIdx.x;
  const int lane = t & 63;
  const int wm = t >> 7, wn = (t >> 6) & 1;
  const int m0 = mt * 128, n0 = blockIdx.y * 128;

  __shared__ __align__(16) unsigned char lA[16384];
  __shared__ __align__(16) unsigned char lBg[16384];
  __shared__ __align__(16) unsigned char lBu[16384];

  size_t aoff[4], boff[4];
  int dsto[4];
  #pragma unroll
  for (int i = 0; i < 4; ++i) {
    int flat = i * 4096 + t * 16;
    int row = flat >> 7;
    int kb = (flat & 127) ^ ((row & 7) << 4);
    int ar = m0 + row;
    if (GATHER) ar = rl[ar < cnt ? ar : cnt - 1];
    aoff[i] = (size_t)ar * (DIM * 2) + kb;
    boff[i] = (size_t)(n0 + row) * (DIM * 2) + kb;
    dsto[i] = flat;
  }

  f32x4 accg[4][4], accu[4][4];
  #pragma unroll
  for (int i = 0; i < 4; ++i)
    #pragma unroll
    for (int j = 0; j < 4; ++j) {
      accg[i][j] = f32x4{0.f, 0.f, 0.f, 0.f};
      accu[i][j] = f32x4{0.f, 0.f, 0.f, 0.f};
    }

  const char* xc = (const char*)xb;
  const char* gc = (const char*)Bg;
  const char* uc = (const char*)Bu;

  for (int kt = 0; kt < DIM / 64; ++kt) {
    __syncthreads();
    size_t ko = (size_t)kt * 128;
    #pragma unroll
    for (int i = 0; i < 4; ++i) {
      gload16(xc + aoff[i] + ko, lA + dsto[i]);
      gload16(gc + boff[i] + ko, lBg + dsto[i]);
      gload16(uc + boff[i] + ko, lBu + dsto[i]);
    }
    __syncthreads();
    #pragma unroll
    for (int ks = 0; ks < 2; ++ks) {
      bf16x8 af[4], bgf[4], buf_[4];
      int kb = ks * 64 + ((lane >> 4) << 4);
      #pragma unroll
      for (int mi = 0; mi < 4; ++mi) {
        int row = wm * 64 + mi * 16 + (lane & 15);
        af[mi] = *(const bf16x8*)(lA + row * 128 + (kb ^ ((row & 7) << 4)));
      }
      #pragma unroll
      for (int ni = 0; ni < 4; ++ni) {
        int col = wn * 64 + ni * 16 + (lane & 15);
        int o = col * 128 + (kb ^ ((col & 7) << 4));
        bgf[ni] = *(const bf16x8*)(lBg + o);
        buf_[ni] = *(const bf16x8*)(lBu + o);
      }
      #pragma unroll
      for (int mi = 0; mi < 4; ++mi)
        #pragma unroll
        for (int ni = 0; ni < 4; ++ni) {
          accg[mi][ni] = __builtin_amdgcn_mfma_f32_16x16x32_bf16(af[mi], bgf[ni], accg[mi][ni], 0, 0, 0);
          accu[mi][ni] = __builtin_amdgcn_mfma_f32_16x16x32_bf16(af[mi], buf_[ni], accu[mi][ni], 0, 0, 0);
        }
    }
  }

  #pragma unroll
  for (int mi = 0; mi < 4; ++mi) {
    #pragma unroll
    for (int r = 0; r < 4; ++r) {
      int pr = m0 + wm * 64 + mi * 16 + ((lane >> 4) << 2) + r;
      if (GATHER && pr >= cnt) continue;
      int tok = GATHER ? rl[pr] : pr;
      unsigned short* hrow = h + (size_t)tok * EDIM;
      #pragma unroll
      for (int ni = 0; ni < 4; ++ni) {
        int col = n0 + wn * 64 + ni * 16 + (lane & 15);
        float g = accg[mi][ni][r], u = accu[mi][ni][r];
        float s = g / (1.f + __expf(-g));
        hrow[col] = f2bf(s * u);
      }
    }
  }
}

// ---------------- down GEMM: out (+)= h @ Wd ---------------------------------
template<bool GATHER>
__global__ __launch_bounds__(256, 2)
void down_k(const unsigned short* __restrict__ hb, const unsigned short* __restrict__ Bd0,
            const int* __restrict__ counts, const int* __restrict__ rowlist,
            float* __restrict__ out) {
  int mt, cnt;
  const int* rl = nullptr;
  const unsigned short* Bd = Bd0;
  if (GATHER) {
    int e = blockIdx.x >> 6;
    mt = blockIdx.x & 63;
    cnt = counts[e];
    if (mt * 128 >= cnt) return;
    rl = rowlist + e * NTOK;
    Bd = Bd0 + (size_t)e * ((size_t)DIM * EDIM);
  } else { mt = blockIdx.x; cnt = NTOK; }

  const int t = threadIdx.x;
  const int lane = t & 63;
  const int wm = t >> 7, wn = (t >> 6) & 1;
  const int m0 = mt * 128, n0 = blockIdx.y * 128;

  __shared__ __align__(16) unsigned char lA[16384];
  __shared__ __align__(16) unsigned char lB[16384];

  size_t aoff[4], boff[4];
  int dsto[4];
  #pragma unroll
  for (int i = 0; i < 4; ++i) {
    int flat = i * 4096 + t * 16;
    int row = flat >> 7;
    int kb = (flat & 127) ^ ((row & 7) << 4);
    int ar = m0 + row;
    if (GATHER) ar = rl[ar < cnt ? ar : cnt - 1];
    aoff[i] = (size_t)ar * (EDIM * 2) + kb;
    boff[i] = (size_t)(n0 + row) * (EDIM * 2) + kb;
    dsto[i] = flat;
  }

  f32x4 acc[4][4];
  #pragma unroll
  for (int i = 0; i < 4; ++i)
    #pragma unroll
    for (int j = 0; j < 4; ++j) acc[i][j] = f32x4{0.f, 0.f, 0.f, 0.f};

  const char* ac = (const char*)hb;
  const char* bc = (const char*)Bd;

  for (int kt = 0; kt < EDIM / 64; ++kt) {
    __syncthreads();
    size_t ko = (size_t)kt * 128;
    #pragma unroll
    for (int i = 0; i < 4; ++i) {
      gload16(ac + aoff[i] + ko, lA + dsto[i]);
      gload16(bc + boff[i] + ko, lB + dsto[i]);
    }
    __syncthreads();
    #pragma unroll
    for (int ks = 0; ks < 2; ++ks) {
      bf16x8 af[4], bf[4];
      int kb = ks * 64 + ((lane >> 4) << 4);
      #pragma unroll
      for (int mi = 0; mi < 4; ++mi) {
        int row = wm * 64 + mi * 16 + (lane & 15);
        af[mi] = *(const bf16x8*)(lA + row * 128 + (kb ^ ((row & 7) << 4)));
      }
      #pragma unroll
      for (int ni = 0; ni < 4; ++ni) {
        int col = wn * 64 + ni * 16 + (lane & 15);
        bf[ni] = *(const bf16x8*)(lB + col * 128 + (kb ^ ((col & 7) << 4)));
      }
      #pragma unroll
      for (int mi = 0; mi < 4; ++mi)
        #pragma unroll
        for (int ni = 0; ni < 4; ++ni)
          acc[mi][ni] = __builtin_amdgcn_mfma_f32_16x16x32_bf16(af[mi], bf[ni], acc[mi][ni], 0, 0, 0);
    }
  }

  #pragma unroll
  for (int mi = 0; mi < 4; ++mi) {
    #pragma unroll
    for (int r = 0; r < 4; ++r) {
      int pr = m0 + wm * 64 + mi * 16 + ((lane >> 4) << 2) + r;
      if (GATHER && pr >= cnt) continue;
      int tok = GATHER ? rl[pr] : pr;
      float* orow = out + (size_t)tok * DIM;
      #pragma unroll
      for (int ni = 0; ni < 4; ++ni) {
        int col = n0 + wn * 64 + ni * 16 + (lane & 15);
        float v = acc[mi][ni][r];
        if (GATHER) orow[col] += v; else orow[col] = v;
      }
    }
  }
}

extern "C" void kernel_launch(void* const* d_in, const int* in_sizes, int n_in,
                              void* d_out, int out_size, void* d_ws, size_t ws_size,
                              hipStream_t stream) {
  const float* x  = (const float*)d_in[0];
  const float* Wr = (const float*)d_in[1];
  const float* rb = (const float*)d_in[2];
  const float* Wg = (const float*)d_in[3];
  const float* Wu = (const float*)d_in[4];
  const float* Wd = (const float*)d_in[5];
  const float* Sg = (const float*)d_in[6];
  const float* Su = (const float*)d_in[7];
  const float* Sd = (const float*)d_in[8];
  float* out = (float*)d_out;

  const size_t MSZ = (size_t)DIM * EDIM;   // 2,097,152 elements per weight matrix
  char* ws = (char*)d_ws;
  int* counts  = (int*)ws;                               // 8 B (padded to 256)
  int* rowlist = (int*)(ws + 256);                       // 2*8192*4 = 64 KiB
  unsigned short* xb = (unsigned short*)(ws + 256 + 65536);
  unsigned short* wt = xb + (size_t)NTOK * DIM;          // 9 transposed bf16 matrices
  unsigned short* h  = wt + 9 * MSZ;                     // [NTOK][EDIM] bf16

  const unsigned short* Sgt = wt + 0 * MSZ;  // [EDIM][DIM]
  const unsigned short* Sut = wt + 1 * MSZ;  // [EDIM][DIM]
  const unsigned short* Sdt = wt + 2 * MSZ;  // [DIM][EDIM]
  const unsigned short* Wgt = wt + 3 * MSZ;  // 2 x [EDIM][DIM]
  const unsigned short* Wut = wt + 5 * MSZ;  // 2 x [EDIM][DIM]
  const unsigned short* Wdt = wt + 7 * MSZ;  // 2 x [DIM][EDIM]

  cvt_x_k<<<4096, 256, 0, stream>>>(x, xb, counts);
  trans_k<<<dim3(2048, 9), dim3(32, 8), 0, stream>>>(Sg, Su, Sd, Wg, Wu, Wd, wt);
  router_k<<<2048, 256, 0, stream>>>(x, Wr, rb, counts, rowlist);

  // shared expert: all rows
  up_k<false><<<dim3(64, 16), 256, 0, stream>>>(xb, Sgt, Sut, nullptr, nullptr, h);
  down_k<false><<<dim3(64, 8), 256, 0, stream>>>(h, Sdt, nullptr, nullptr, out);
  // routed experts: gathered rows, accumulate into out
  up_k<true><<<dim3(128, 16), 256, 0, stream>>>(xb, Wgt, Wut, counts, rowlist, h);
  down_k<true><<<dim3(128, 8), 256, 0, stream>>>(h, Wdt, counts, rowlist, out);
}

// Round 2
// 284.297 us; speedup vs baseline: 1.3320x; 1.3320x over previous
//
#include <hip/hip_runtime.h>
#include <stdint.h>

#define NTOK 8192
#define DIM 1024
#define EDIM 2048

typedef __attribute__((ext_vector_type(8))) short bf16x8;
typedef __attribute__((ext_vector_type(4))) float f32x4;

__device__ __forceinline__ unsigned short f2bf(float f) {
  union { float f; unsigned u; } v; v.f = f;
  unsigned r = (v.u + 0x7FFF + ((v.u >> 16) & 1)) >> 16;
  return (unsigned short)r;
}

__device__ __forceinline__ void gload16(const void* g, void* l) {
  __builtin_amdgcn_global_load_lds(
      (const __attribute__((address_space(1))) unsigned int*)g,
      (__attribute__((address_space(3))) unsigned int*)l, 16, 0, 0);
}

// ---- fused x->bf16 cast + router logits (no atomics; writes choice[n]) ------
__global__ void cvtrouter_k(const float* __restrict__ x, const float* __restrict__ Wr,
                            const float* __restrict__ bias,
                            unsigned short* __restrict__ xb, int* __restrict__ choice) {
  const int wid = threadIdx.x >> 6, lane = threadIdx.x & 63;
  const float b0 = bias[0], b1 = bias[1];
  const float2* wr = (const float2*)Wr;
  #pragma unroll
  for (int r = 0; r < 2; ++r) {
    const int n = blockIdx.x * 8 + wid * 2 + r;
    const float4* xr = (const float4*)(x + (size_t)n * DIM);
    uint2* xo = (uint2*)(xb + (size_t)n * DIM);
    float s0 = 0.f, s1 = 0.f;
    #pragma unroll
    for (int i = 0; i < 4; ++i) {
      const int idx = i * 64 + lane;
      float4 v = xr[idx];
      float2 wa = wr[idx * 4], wb = wr[idx * 4 + 1], wc = wr[idx * 4 + 2], wd = wr[idx * 4 + 3];
      s0 += v.x * wa.x + v.y * wb.x + v.z * wc.x + v.w * wd.x;
      s1 += v.x * wa.y + v.y * wb.y + v.z * wc.y + v.w * wd.y;
      union { unsigned short s[4]; uint2 u; } o;
      o.s[0] = f2bf(v.x); o.s[1] = f2bf(v.y); o.s[2] = f2bf(v.z); o.s[3] = f2bf(v.w);
      xo[idx] = o.u;
    }
    #pragma unroll
    for (int off = 32; off; off >>= 1) {
      s0 += __shfl_xor(s0, off);
      s1 += __shfl_xor(s1, off);
    }
    if (lane == 0) choice[n] = (s1 + b1 > s0 + b0) ? 1 : 0;
  }
}

// ---- single-block prefix scan: choice[] -> ordered rowlists + counts --------
__global__ void scan_k(const int* __restrict__ choice, int* __restrict__ counts,
                       int* __restrict__ rowlist) {
  const int t = threadIdx.x;            // 1024 threads, one block
  const int base = t * 8;
  int c[8]; int ones = 0;
  #pragma unroll
  for (int j = 0; j < 8; ++j) { c[j] = choice[base + j]; ones += c[j]; }
  const int lane = t & 63, wid = t >> 6;
  int v = ones;
  #pragma unroll
  for (int off = 1; off < 64; off <<= 1) {
    int o = __shfl_up(v, off);
    if (lane >= off) v += o;
  }
  __shared__ int wsum[16];
  if (lane == 63) wsum[wid] = v;
  __syncthreads();
  int pre = 0, tot = 0;
  #pragma unroll
  for (int w = 0; w < 16; ++w) {
    int s = wsum[w];
    if (w < wid) pre += s;
    tot += s;
  }
  const int excl = pre + v - ones;      // exclusive prefix of ones before token base
  int p0 = base - excl;
  int p1 = excl;
  #pragma unroll
  for (int j = 0; j < 8; ++j) {
    if (c[j]) rowlist[NTOK + p1++] = base + j;
    else rowlist[p0++] = base + j;
  }
  if (t == 0) { counts[0] = NTOK - tot; counts[1] = tot; }
}

// ---------------- transpose + cast all weight matrices to [N][K] bf16 --------
__global__ void trans_k(const float* __restrict__ Sg, const float* __restrict__ Su,
                        const float* __restrict__ Sd, const float* __restrict__ Wg,
                        const float* __restrict__ Wu, const float* __restrict__ Wd,
                        unsigned short* __restrict__ wt) {
  const int id = blockIdx.y;
  const size_t MSZ = (size_t)DIM * EDIM;
  const float* src; int R, C;
  switch (id) {
    case 0: src = Sg;       R = DIM;  C = EDIM; break;
    case 1: src = Su;       R = DIM;  C = EDIM; break;
    case 2: src = Sd;       R = EDIM; C = DIM;  break;
    case 3: src = Wg;       R = DIM;  C = EDIM; break;
    case 4: src = Wg + MSZ; R = DIM;  C = EDIM; break;
    case 5: src = Wu;       R = DIM;  C = EDIM; break;
    case 6: src = Wu + MSZ; R = DIM;  C = EDIM; break;
    case 7: src = Wd;       R = EDIM; C = DIM;  break;
    default: src = Wd + MSZ; R = EDIM; C = DIM;  break;
  }
  unsigned short* dst = wt + (size_t)id * MSZ;
  __shared__ float tile[32][33];
  int tC = C >> 5;
  int tr = blockIdx.x / tC, tc = blockIdx.x % tC;
  int xt = threadIdx.x, yt = threadIdx.y;
  #pragma unroll
  for (int j = 0; j < 4; ++j)
    tile[yt + j * 8][xt] = src[(size_t)(tr * 32 + yt + j * 8) * C + tc * 32 + xt];
  __syncthreads();
  #pragma unroll
  for (int j = 0; j < 4; ++j)
    dst[(size_t)(tc * 32 + yt + j * 8) * R + tr * 32 + xt] = f2bf(tile[xt][yt + j * 8]);
}

// ---------------- fused gate+up GEMM -> h = silu(x@Wg)*(x@Wu), bf16 ----------
template<bool GATHER>
__global__ __launch_bounds__(256, 2)
void up_k(const unsigned short* __restrict__ xb, const unsigned short* __restrict__ Bg0,
          const unsigned short* __restrict__ Bu0, const int* __restrict__ counts,
          const int* __restrict__ rowlist, unsigned short* __restrict__ h) {
  int mt, cnt;
  const int* rl = nullptr;
  const unsigned short* Bg = Bg0;
  const unsigned short* Bu = Bu0;
  if (GATHER) {
    int e = blockIdx.x >> 6;
    mt = blockIdx.x & 63;
    cnt = counts[e];
    if (mt * 128 >= cnt) return;
    rl = rowlist + e * NTOK;
    size_t off = (size_t)e * ((size_t)DIM * EDIM);
    Bg = Bg0 + off; Bu = Bu0 + off;
  } else { mt = blockIdx.x; cnt = NTOK; }

  const int t = threadIdx.x;
  const int lane = t & 63;
  const int wm = t >> 7, wn = (t >> 6) & 1;
  const int m0 = mt * 128, n0 = blockIdx.y * 128;

  __shared__ __align__(16) unsigned char lA[16384];
  __shared__ __align__(16) unsigned char lBg[16384];
  __shared__ __align__(16) unsigned char lBu[16384];

  size_t aoff[4], boff[4];
  int dsto[4];
  #pragma unroll
  for (int i = 0; i < 4; ++i) {
    int flat = i * 4096 + t * 16;
    int row = flat >> 7;
    int kb = (flat & 127) ^ ((row & 7) << 4);
    int ar = m0 + row;
    if (GATHER) ar = rl[ar < cnt ? ar : cnt - 1];
    aoff[i] = (size_t)ar * (DIM * 2) + kb;
    boff[i] = (size_t)(n0 + row) * (DIM * 2) + kb;
    dsto[i] = flat;
  }

  f32x4 accg[4][4], accu[4][4];
  #pragma unroll
  for (int i = 0; i < 4; ++i)
    #pragma unroll
    for (int j = 0; j < 4; ++j) {
      accg[i][j] = f32x4{0.f, 0.f, 0.f, 0.f};
      accu[i][j] = f32x4{0.f, 0.f, 0.f, 0.f};
    }

  const char* xc = (const char*)xb;
  const char* gc = (const char*)Bg;
  const char* uc = (const char*)Bu;

  for (int kt = 0; kt < DIM / 64; ++kt) {
    __syncthreads();
    size_t ko = (size_t)kt * 128;
    #pragma unroll
    for (int i = 0; i < 4; ++i) {
      gload16(xc + aoff[i] + ko, lA + dsto[i]);
      gload16(gc + boff[i] + ko, lBg + dsto[i]);
      gload16(uc + boff[i] + ko, lBu + dsto[i]);
    }
    __syncthreads();
    #pragma unroll
    for (int ks = 0; ks < 2; ++ks) {
      bf16x8 af[4], bgf[4], buf_[4];
      int kb = ks * 64 + ((lane >> 4) << 4);
      #pragma unroll
      for (int mi = 0; mi < 4; ++mi) {
        int row = wm * 64 + mi * 16 + (lane & 15);
        af[mi] = *(const bf16x8*)(lA + row * 128 + (kb ^ ((row & 7) << 4)));
      }
      #pragma unroll
      for (int ni = 0; ni < 4; ++ni) {
        int col = wn * 64 + ni * 16 + (lane & 15);
        int o = col * 128 + (kb ^ ((col & 7) << 4));
        bgf[ni] = *(const bf16x8*)(lBg + o);
        buf_[ni] = *(const bf16x8*)(lBu + o);
      }
      #pragma unroll
      for (int mi = 0; mi < 4; ++mi)
        #pragma unroll
        for (int ni = 0; ni < 4; ++ni) {
          accg[mi][ni] = __builtin_amdgcn_mfma_f32_16x16x32_bf16(af[mi], bgf[ni], accg[mi][ni], 0, 0, 0);
          accu[mi][ni] = __builtin_amdgcn_mfma_f32_16x16x32_bf16(af[mi], buf_[ni], accu[mi][ni], 0, 0, 0);
        }
    }
  }

  #pragma unroll
  for (int mi = 0; mi < 4; ++mi) {
    #pragma unroll
    for (int r = 0; r < 4; ++r) {
      int pr = m0 + wm * 64 + mi * 16 + ((lane >> 4) << 2) + r;
      if (GATHER && pr >= cnt) continue;
      int tok = GATHER ? rl[pr] : pr;
      unsigned short* hrow = h + (size_t)tok * EDIM;
      #pragma unroll
      for (int ni = 0; ni < 4; ++ni) {
        int col = n0 + wn * 64 + ni * 16 + (lane & 15);
        float g = accg[mi][ni][r], u = accu[mi][ni][r];
        float s = g / (1.f + __expf(-g));
        hrow[col] = f2bf(s * u);
      }
    }
  }
}

// ---------------- down GEMM: out (+)= h @ Wd ---------------------------------
template<bool GATHER>
__global__ __launch_bounds__(256, 2)
void down_k(const unsigned short* __restrict__ hb, const unsigned short* __restrict__ Bd0,
            const int* __restrict__ counts, const int* __restrict__ rowlist,
            float* __restrict__ out) {
  int mt, cnt;
  const int* rl = nullptr;
  const unsigned short* Bd = Bd0;
  if (GATHER) {
    int e = blockIdx.x >> 6;
    mt = blockIdx.x & 63;
    cnt = counts[e];
    if (mt * 128 >= cnt) return;
    rl = rowlist + e * NTOK;
    Bd = Bd0 + (size_t)e * ((size_t)DIM * EDIM);
  } else { mt = blockIdx.x; cnt = NTOK; }

  const int t = threadIdx.x;
  const int lane = t & 63;
  const int wm = t >> 7, wn = (t >> 6) & 1;
  const int m0 = mt * 128, n0 = blockIdx.y * 128;

  __shared__ __align__(16) unsigned char lA[16384];
  __shared__ __align__(16) unsigned char lB[16384];

  size_t aoff[4], boff[4];
  int dsto[4];
  #pragma unroll
  for (int i = 0; i < 4; ++i) {
    int flat = i * 4096 + t * 16;
    int row = flat >> 7;
    int kb = (flat & 127) ^ ((row & 7) << 4);
    int ar = m0 + row;
    if (GATHER) ar = rl[ar < cnt ? ar : cnt - 1];
    aoff[i] = (size_t)ar * (EDIM * 2) + kb;
    boff[i] = (size_t)(n0 + row) * (EDIM * 2) + kb;
    dsto[i] = flat;
  }

  f32x4 acc[4][4];
  #pragma unroll
  for (int i = 0; i < 4; ++i)
    #pragma unroll
    for (int j = 0; j < 4; ++j) acc[i][j] = f32x4{0.f, 0.f, 0.f, 0.f};

  const char* ac = (const char*)hb;
  const char* bc = (const char*)Bd;

  for (int kt = 0; kt < EDIM / 64; ++kt) {
    __syncthreads();
    size_t ko = (size_t)kt * 128;
    #pragma unroll
    for (int i = 0; i < 4; ++i) {
      gload16(ac + aoff[i] + ko, lA + dsto[i]);
      gload16(bc + boff[i] + ko, lB + dsto[i]);
    }
    __syncthreads();
    #pragma unroll
    for (int ks = 0; ks < 2; ++ks) {
      bf16x8 af[4], bf[4];
      int kb = ks * 64 + ((lane >> 4) << 4);
      #pragma unroll
      for (int mi = 0; mi < 4; ++mi) {
        int row = wm * 64 + mi * 16 + (lane & 15);
        af[mi] = *(const bf16x8*)(lA + row * 128 + (kb ^ ((row & 7) << 4)));
      }
      #pragma unroll
      for (int ni = 0; ni < 4; ++ni) {
        int col = wn * 64 + ni * 16 + (lane & 15);
        bf[ni] = *(const bf16x8*)(lB + col * 128 + (kb ^ ((col & 7) << 4)));
      }
      #pragma unroll
      for (int mi = 0; mi < 4; ++mi)
        #pragma unroll
        for (int ni = 0; ni < 4; ++ni)
          acc[mi][ni] = __builtin_amdgcn_mfma_f32_16x16x32_bf16(af[mi], bf[ni], acc[mi][ni], 0, 0, 0);
    }
  }

  #pragma unroll
  for (int mi = 0; mi < 4; ++mi) {
    #pragma unroll
    for (int r = 0; r < 4; ++r) {
      int pr = m0 + wm * 64 + mi * 16 + ((lane >> 4) << 2) + r;
      if (GATHER && pr >= cnt) continue;
      int tok = GATHER ? rl[pr] : pr;
      float* orow = out + (size_t)tok * DIM;
      #pragma unroll
      for (int ni = 0; ni < 4; ++ni) {
        int col = n0 + wn * 64 + ni * 16 + (lane & 15);
        float v = acc[mi][ni][r];
        if (GATHER) orow[col] += v; else orow[col] = v;
      }
    }
  }
}

extern "C" void kernel_launch(void* const* d_in, const int* in_sizes, int n_in,
                              void* d_out, int out_size, void* d_ws, size_t ws_size,
                              hipStream_t stream) {
  const float* x  = (const float*)d_in[0];
  const float* Wr = (const float*)d_in[1];
  const float* rb = (const float*)d_in[2];
  const float* Wg = (const float*)d_in[3];
  const float* Wu = (const float*)d_in[4];
  const float* Wd = (const float*)d_in[5];
  const float* Sg = (const float*)d_in[6];
  const float* Su = (const float*)d_in[7];
  const float* Sd = (const float*)d_in[8];
  float* out = (float*)d_out;

  const size_t MSZ = (size_t)DIM * EDIM;   // 2,097,152 elements per weight matrix
  char* ws = (char*)d_ws;
  int* counts  = (int*)ws;                               // 8 B (padded to 256)
  int* choice  = (int*)(ws + 256);                       // 8192*4 = 32 KiB
  int* rowlist = (int*)(ws + 256 + 32768);               // 2*8192*4 = 64 KiB
  unsigned short* xb = (unsigned short*)(ws + 256 + 32768 + 65536);
  unsigned short* wt = xb + (size_t)NTOK * DIM;          // 9 transposed bf16 matrices
  unsigned short* h  = wt + 9 * MSZ;                     // [NTOK][EDIM] bf16

  const unsigned short* Sgt = wt + 0 * MSZ;  // [EDIM][DIM]
  const unsigned short* Sut = wt + 1 * MSZ;  // [EDIM][DIM]
  const unsigned short* Sdt = wt + 2 * MSZ;  // [DIM][EDIM]
  const unsigned short* Wgt = wt + 3 * MSZ;  // 2 x [EDIM][DIM]
  const unsigned short* Wut = wt + 5 * MSZ;  // 2 x [EDIM][DIM]
  const unsigned short* Wdt = wt + 7 * MSZ;  // 2 x [DIM][EDIM]

  cvtrouter_k<<<1024, 256, 0, stream>>>(x, Wr, rb, xb, choice);
  scan_k<<<1, 1024, 0, stream>>>(choice, counts, rowlist);
  trans_k<<<dim3(2048, 9), dim3(32, 8), 0, stream>>>(Sg, Su, Sd, Wg, Wu, Wd, wt);

  // shared expert: all rows
  up_k<false><<<dim3(64, 16), 256, 0, stream>>>(xb, Sgt, Sut, nullptr, nullptr, h);
  down_k<false><<<dim3(64, 8), 256, 0, stream>>>(h, Sdt, nullptr, nullptr, out);
  // routed experts: gathered rows, accumulate into out
  up_k<true><<<dim3(128, 16), 256, 0, stream>>>(xb, Wgt, Wut, counts, rowlist, h);
  down_k<true><<<dim3(128, 8), 256, 0, stream>>>(h, Wdt, counts, rowlist, out);
}